// Round 24
// baseline (1512.557 us; speedup 1.0000x reference)
//
#include <hip/hip_runtime.h>
#include <math.h>

// Problem constants
#define BTOT   4096
#define CIN    3
#define TIN    64
#define SIN    128

// ws layout (float offsets)
#define SEQ_OFF    0                            // [4096][60][124]
#define G_OFF      (SEQ_OFF + 4096*60*124)      // [4096][129]
#define HST_OFF    (G_OFF + 4096*129)           // [4096][132] h state between chunks
#define AWHH_OFF   (HST_OFF + 4096*132)         // [25][5][2][64][8] bf16 Whh frags
#define AWIH_OFF   (AWHH_OFF + 64000)           // [25][4][2][64][8] bf16 Wih frags
#define MUWP_OFF   (AWIH_OFF + 51200)           // [129][260]
#define LSWP_OFF   (MUWP_OFF + 129*260)         // [129][260]
#define BUF_OFF    (LSWP_OFF + 129*260)         // seqbf[CT][32][10240 ull] ++ gic[CT][387][4096]

// per-t float sizes for chunking
#define PER_T_GIC   (387 * 4096)
#define PER_T_SBF   655360                       // 32*40960 shorts = 655360 float slots
#define SBF_T_SH    1310720                      // shorts per t

typedef __attribute__((ext_vector_type(8))) short bf16x8;
typedef __attribute__((ext_vector_type(4))) float f32x4;

// Inline transcendentals (no libm calls in hot loops)
__device__ __forceinline__ float fast_tanh(float x) {
    float ax = fabsf(x);
    float t  = __expf(-2.f * ax);
    float r  = (1.f - t) / (1.f + t);
    return copysignf(r, x);
}
__device__ __forceinline__ float fast_sigmoid(float x) {
    return 1.f / (1.f + __expf(-x));
}
// bf16 round-to-nearest-even helpers (bit ops only)
__device__ __forceinline__ unsigned short f2bf(float x) {
    unsigned int u = __float_as_uint(x);
    unsigned int r = u + 0x7FFFu + ((u >> 16) & 1u);
    return (unsigned short)(r >> 16);
}
__device__ __forceinline__ float bf2f(unsigned short b) {
    return __uint_as_float(((unsigned int)b) << 16);
}

// ---------------------------------------------------------------------------
// Prep: bf16 hi/lo fragment tables for Whh (5 k-tiles) and Wih (4 k-tiles),
// plus fc weight padding. (Passing R18-R23.)
// ---------------------------------------------------------------------------
__global__ __launch_bounds__(256) void prep_pad(
    const float* __restrict__ Whh, const float* __restrict__ Wih,
    const float* __restrict__ muw, const float* __restrict__ lsw,
    float* __restrict__ ws)
{
    int idx = blockIdx.x * 256 + threadIdx.x;
    const int NHH = 25 * 5 * 2 * 512;   // 128000 shorts
    const int NIA = 25 * 4 * 2 * 512;   // 102400 shorts
    const int N2  = 129 * 260;
    if (idx < NHH) {
        int a      = idx;
        int frag   = a >> 9;
        int within = a & 511;
        int l      = within >> 3;
        int c      = within & 7;
        int half   = frag & 1;
        int q      = frag >> 1;
        int kt     = q % 5;
        int jt     = q / 5;
        int j      = jt * 16 + (l & 15);
        int k      = kt * 32 + (l >> 4) * 8 + c;
        float v    = (j < 387 && k < 129) ? Whh[(size_t)j * 129 + k] : 0.f;
        unsigned short hb = f2bf(v);
        ((short*)(ws + AWHH_OFF))[a] = (short)((half == 0) ? hb : f2bf(v - bf2f(hb)));
    } else if (idx < NHH + NIA) {
        int a      = idx - NHH;
        int frag   = a >> 9;
        int within = a & 511;
        int l      = within >> 3;
        int c      = within & 7;
        int half   = frag & 1;
        int q      = frag >> 1;
        int kt     = q & 3;
        int jt     = q >> 2;
        int j      = jt * 16 + (l & 15);
        int k      = kt * 32 + (l >> 4) * 8 + c;
        float v    = (j < 387 && k < 124) ? Wih[(size_t)j * 124 + k] : 0.f;
        unsigned short hb = f2bf(v);
        ((short*)(ws + AWIH_OFF))[a] = (short)((half == 0) ? hb : f2bf(v - bf2f(hb)));
    } else if (idx < NHH + NIA + N2) {
        int i = idx - NHH - NIA; int j = i / 260, k = i - j * 260;
        ws[MUWP_OFF + i] = (k < 258) ? muw[j * 258 + k] : 0.f;
    } else if (idx < NHH + NIA + 2 * N2) {
        int i = idx - NHH - NIA - N2; int j = i / 260, k = i - j * 260;
        ws[LSWP_OFF + i] = (k < 258) ? lsw[j * 258 + k] : 0.f;
    }
}

// ---------------------------------------------------------------------------
// conv_fused v3 — passing R21/R23 (unchanged; 3-set window is its no-spill
// local optimum per R22).
// ---------------------------------------------------------------------------
#define RACC(F4_, F2_, W0_, W1_, W2_) \
    acc0 += (F4_).x*(W0_) + (F4_).y*(W1_) + (F4_).z*(W2_); \
    acc1 += (F4_).y*(W0_) + (F4_).z*(W1_) + (F4_).w*(W2_); \
    acc2 += (F4_).z*(W0_) + (F4_).w*(W1_) + (F2_).x*(W2_); \
    acc3 += (F4_).w*(W0_) + (F2_).x*(W1_) + (F2_).y*(W2_);

#define LDSET(S, TR_) { \
    S##0_4 = *(const float4*)(xc0 + (TR_) * 128 + s0); \
    S##0_2 = *(const float2*)(xc0 + (TR_) * 128 + f2c); \
    S##1_4 = *(const float4*)(xc1 + (TR_) * 128 + s0); \
    S##1_2 = *(const float2*)(xc1 + (TR_) * 128 + f2c); \
    S##2_4 = *(const float4*)(xc2 + (TR_) * 128 + s0); \
    S##2_2 = *(const float2*)(xc2 + (TR_) * 128 + f2c); }

#define C1STEP(SA, SB, SC, TQ_) { \
    float acc0 = bo, acc1 = bo, acc2 = bo, acc3 = bo; \
    RACC(SA##0_4, SA##0_2, w000, w001, w002) \
    RACC(SA##1_4, SA##1_2, w100, w101, w102) \
    RACC(SA##2_4, SA##2_2, w200, w201, w202) \
    RACC(SB##0_4, SB##0_2, w010, w011, w012) \
    RACC(SB##1_4, SB##1_2, w110, w111, w112) \
    RACC(SB##2_4, SB##2_2, w210, w211, w212) \
    RACC(SC##0_4, SC##0_2, w020, w021, w022) \
    RACC(SC##1_4, SC##1_2, w120, w121, w122) \
    RACC(SC##2_4, SC##2_2, w220, w221, w222) \
    float4 r_; \
    r_.x = (acc0 >= 0.f) ? acc0 : 0.01f * acc0; \
    r_.y = (acc1 >= 0.f) ? acc1 : 0.01f * acc1; \
    r_.z = (acc2 >= 0.f) ? acc2 : 0.01f * acc2; \
    r_.w = (acc3 >= 0.f) ? acc3 : 0.01f * acc3; \
    *(float4*)(h1t + (o * 12 + (TQ_)) * 128 + s0) = r_; }

#define C2SEG(o_, kt_, W0_, W1_, W2_) { \
    const float* rp_ = h1t + ((o_) * 12 + tq + (kt_)) * 128 + s0; \
    float4 v4_ = *(const float4*)rp_; \
    float2 v2_ = *(const float2*)(rp_ + 4); \
    acc0 += v4_.x*(W0_) + v4_.y*(W1_) + v4_.z*(W2_); \
    acc1 += v4_.y*(W0_) + v4_.z*(W1_) + v4_.w*(W2_); \
    acc2 += v4_.z*(W0_) + v4_.w*(W1_) + v2_.x*(W2_); \
    acc3 += v4_.w*(W0_) + v2_.x*(W1_) + v2_.y*(W2_); }

__global__ __launch_bounds__(256) void conv_fused(
    const float* __restrict__ x,
    const float* __restrict__ w1, const float* __restrict__ b1,
    const float* __restrict__ w2, const float* __restrict__ b2,
    float* __restrict__ seq)
{
    __shared__ __attribute__((aligned(16))) float h1t[6 * 12 * 128];
    __shared__ float w1s[162];
    __shared__ float w2s[54];
    __shared__ float b1s[6];
    __shared__ float b2s;

    const int tid  = threadIdx.x;
    const int tile = blockIdx.x;   // 0..5
    const int bb   = blockIdx.y;   // batch
    const int T0   = tile * 10;

    if (tid < 162)                  w1s[tid] = w1[tid];
    if (tid >= 192 && tid < 246)    w2s[tid - 192] = w2[tid - 192];
    if (tid >= 248 && tid < 254)    b1s[tid - 248] = b1[tid - 248];
    if (tid == 255)                 b2s = b2[0];
    __syncthreads();

    if (tid < 192) {
        const int o   = tid >> 5;
        const int s0  = (tid & 31) * 4;
        const int f2c = (s0 < 124) ? (s0 + 4) : 122;   // clamp: junk cols only
        const float* wb = w1s + o * 27;
        float w000 = wb[0],  w001 = wb[1],  w002 = wb[2];
        float w010 = wb[3],  w011 = wb[4],  w012 = wb[5];
        float w020 = wb[6],  w021 = wb[7],  w022 = wb[8];
        float w100 = wb[9],  w101 = wb[10], w102 = wb[11];
        float w110 = wb[12], w111 = wb[13], w112 = wb[14];
        float w120 = wb[15], w121 = wb[16], w122 = wb[17];
        float w200 = wb[18], w201 = wb[19], w202 = wb[20];
        float w210 = wb[21], w211 = wb[22], w212 = wb[23];
        float w220 = wb[24], w221 = wb[25], w222 = wb[26];
        float bo = b1s[o];

        const float* xc0 = x + (size_t)bb * (3 * 64 * 128) + (size_t)T0 * 128;
        const float* xc1 = xc0 + 64 * 128;
        const float* xc2 = xc0 + 2 * 64 * 128;

        float4 A0_4, A1_4, A2_4, B0_4, B1_4, B2_4, C0_4, C1_4, C2_4;
        float2 A0_2, A1_2, A2_2, B0_2, B1_2, B2_2, C0_2, C1_2, C2_2;

        LDSET(A, 0)
        LDSET(B, 1)
        LDSET(C, 2)  C1STEP(A, B, C, 0)
        LDSET(A, 3)  C1STEP(B, C, A, 1)
        LDSET(B, 4)  C1STEP(C, A, B, 2)
        LDSET(C, 5)  C1STEP(A, B, C, 3)
        LDSET(A, 6)  C1STEP(B, C, A, 4)
        LDSET(B, 7)  C1STEP(C, A, B, 5)
        LDSET(C, 8)  C1STEP(A, B, C, 6)
        LDSET(A, 9)  C1STEP(B, C, A, 7)
        LDSET(B, 10) C1STEP(C, A, B, 8)
        LDSET(C, 11) C1STEP(A, B, C, 9)
        LDSET(A, 12) C1STEP(B, C, A, 10)
        LDSET(B, 13) C1STEP(C, A, B, 11)
    }
    __syncthreads();

    {
        float u000 = w2s[0],  u001 = w2s[1],  u002 = w2s[2];
        float u010 = w2s[3],  u011 = w2s[4],  u012 = w2s[5];
        float u020 = w2s[6],  u021 = w2s[7],  u022 = w2s[8];
        float u100 = w2s[9],  u101 = w2s[10], u102 = w2s[11];
        float u110 = w2s[12], u111 = w2s[13], u112 = w2s[14];
        float u120 = w2s[15], u121 = w2s[16], u122 = w2s[17];
        float u200 = w2s[18], u201 = w2s[19], u202 = w2s[20];
        float u210 = w2s[21], u211 = w2s[22], u212 = w2s[23];
        float u220 = w2s[24], u221 = w2s[25], u222 = w2s[26];
        float u300 = w2s[27], u301 = w2s[28], u302 = w2s[29];
        float u310 = w2s[30], u311 = w2s[31], u312 = w2s[32];
        float u320 = w2s[33], u321 = w2s[34], u322 = w2s[35];
        float u400 = w2s[36], u401 = w2s[37], u402 = w2s[38];
        float u410 = w2s[39], u411 = w2s[40], u412 = w2s[41];
        float u420 = w2s[42], u421 = w2s[43], u422 = w2s[44];
        float u500 = w2s[45], u501 = w2s[46], u502 = w2s[47];
        float u510 = w2s[48], u511 = w2s[49], u512 = w2s[50];
        float u520 = w2s[51], u521 = w2s[52], u522 = w2s[53];
        float bo2 = b2s;
        for (int idx = tid; idx < 310; idx += 256) {
            const int tq = idx / 31;
            const int s0 = (idx - tq * 31) * 4;
            float acc0 = bo2, acc1 = bo2, acc2 = bo2, acc3 = bo2;
            C2SEG(0, 0, u000, u001, u002)
            C2SEG(0, 1, u010, u011, u012)
            C2SEG(0, 2, u020, u021, u022)
            C2SEG(1, 0, u100, u101, u102)
            C2SEG(1, 1, u110, u111, u112)
            C2SEG(1, 2, u120, u121, u122)
            C2SEG(2, 0, u200, u201, u202)
            C2SEG(2, 1, u210, u211, u212)
            C2SEG(2, 2, u220, u221, u222)
            C2SEG(3, 0, u300, u301, u302)
            C2SEG(3, 1, u310, u311, u312)
            C2SEG(3, 2, u320, u321, u322)
            C2SEG(4, 0, u400, u401, u402)
            C2SEG(4, 1, u410, u411, u412)
            C2SEG(4, 2, u420, u421, u422)
            C2SEG(5, 0, u500, u501, u502)
            C2SEG(5, 1, u510, u511, u512)
            C2SEG(5, 2, u520, u521, u522)
            float4 r;
            r.x = (acc0 >= 0.f) ? acc0 : 0.01f * acc0;
            r.y = (acc1 >= 0.f) ? acc1 : 0.01f * acc1;
            r.z = (acc2 >= 0.f) ? acc2 : 0.01f * acc2;
            r.w = (acc3 >= 0.f) ? acc3 : 0.01f * acc3;
            *(float4*)(seq + ((size_t)bb * 60 + T0 + tq) * 124 + s0) = r;
        }
    }
}

// ---------------------------------------------------------------------------
// seq2bf — passing R21/R23 (unchanged).
// ---------------------------------------------------------------------------
__global__ __launch_bounds__(256) void seq2bf(
    const float* __restrict__ seq, unsigned long long* __restrict__ sbf,
    int t0, int nt)
{
    long a = (long)blockIdx.x * 256 + threadIdx.x;
    if (a >= (long)nt * 327680) return;
    int tt  = (int)(a / 327680);
    int u   = (int)(a - (long)tt * 327680);
    int chunk = u / 10240;
    int q   = u - chunk * 10240;
    int c0  = (q & 1) * 4;  q >>= 1;
    int ksub = q % 5;       q /= 5;
    int bi  = q & 127;
    int frag = q >> 7;       // 0..7
    int half = frag & 1;
    int kt   = frag >> 1;
    int k0   = kt * 32 + ksub * 8 + c0;

    unsigned long long outp = 0ull;
    if (ksub < 4 && k0 < 124) {
        float4 v = *(const float4*)(seq +
            ((size_t)(chunk * 128 + bi) * 60 + (t0 + tt)) * 124 + k0);
        unsigned short s0, s1, s2, s3;
        if (half == 0) {
            s0 = f2bf(v.x); s1 = f2bf(v.y); s2 = f2bf(v.z); s3 = f2bf(v.w);
        } else {
            s0 = f2bf(v.x - bf2f(f2bf(v.x)));
            s1 = f2bf(v.y - bf2f(f2bf(v.y)));
            s2 = f2bf(v.z - bf2f(f2bf(v.z)));
            s3 = f2bf(v.w - bf2f(f2bf(v.w)));
        }
        outp = (unsigned long long)s0 | ((unsigned long long)s1 << 16)
             | ((unsigned long long)s2 << 32) | ((unsigned long long)s3 << 48);
    }
    sbf[a] = outp;
}

// ---------------------------------------------------------------------------
// gi via MFMA v2 — passing R21/R23 (unchanged).
// ---------------------------------------------------------------------------
__global__ __launch_bounds__(512) void gi_mfma(
    const short* __restrict__ sbf, const short* __restrict__ awih,
    float* __restrict__ gic, int nt)
{
    const int tid = threadIdx.x;
    const int l   = tid & 63;
    const int w   = tid >> 6;          // n-tile 0..7
    const int jt  = blockIdx.y;        // 0..24
    const int bx  = blockIdx.x;
    const int b0  = bx * 128;

    const bf16x8* at = (const bf16x8*)awih;
    const int abase = jt * 8 * 64 + l;
    bf16x8 Ah0 = at[abase + 0 * 128];
    bf16x8 Al0 = at[abase + 0 * 128 + 64];
    bf16x8 Ah1 = at[abase + 1 * 128];
    bf16x8 Al1 = at[abase + 1 * 128 + 64];
    bf16x8 Ah2 = at[abase + 2 * 128];
    bf16x8 Al2 = at[abase + 2 * 128 + 64];
    bf16x8 Ah3 = at[abase + 3 * 128];
    bf16x8 Al3 = at[abase + 3 * 128 + 64];

    const int bn   = w * 16 + (l & 15);
    const int ksub = l >> 4;
    const int off0 = bx * 40960 + (bn * 5 + ksub) * 8;
    const int row0 = ksub * 4;

    for (int tt = 0; tt < nt; ++tt) {
        const short* sb = sbf + (size_t)tt * SBF_T_SH + off0;
        f32x4 acc = {0.f, 0.f, 0.f, 0.f};
        #define GI_KT(KT, AH, AL) { \
            bf16x8 bh = *(const bf16x8*)(sb + ((KT) * 2 + 0) * 5120); \
            bf16x8 bl = *(const bf16x8*)(sb + ((KT) * 2 + 1) * 5120); \
            acc = __builtin_amdgcn_mfma_f32_16x16x32_bf16(AL, bh, acc, 0, 0, 0); \
            acc = __builtin_amdgcn_mfma_f32_16x16x32_bf16(AH, bl, acc, 0, 0, 0); \
            acc = __builtin_amdgcn_mfma_f32_16x16x32_bf16(AH, bh, acc, 0, 0, 0); }
        GI_KT(0, Ah0, Al0)
        GI_KT(1, Ah1, Al1)
        GI_KT(2, Ah2, Al2)
        GI_KT(3, Ah3, Al3)
        #undef GI_KT

        float* gt = gic + (size_t)tt * 387 * 4096;
        #pragma unroll
        for (int i = 0; i < 4; ++i) {
            int j = jt * 16 + row0 + i;
            if (j < 387)
                gt[(size_t)j * 4096 + b0 + bn] = acc[i];
        }
    }
}

// ---------------------------------------------------------------------------
// GRU recurrence via MFMA v2 (R24): 256 blocks x 1024 thr = 16 waves
// (4 waves/SIMD, was 8 waves = 2/SIMD). R23 diagnosis: 1 block/CU with 2
// waves/SIMD exposed the ~200cy L2 latency of the per-step A-table reads.
// Wave w owns j-tiles {w} and {16+w} (w<9): 25 tiles exactly covered, A-table
// traffic unchanged, per-wave work halved, VGPR ~90 (2 acc sets) fits 4/SIMD.
// ---------------------------------------------------------------------------
__global__ __launch_bounds__(1024) void gru_mfma(
    const float* __restrict__ gic, const short* __restrict__ awhh,
    const float* __restrict__ bih, const float* __restrict__ bhh,
    float* __restrict__ hstate, float* __restrict__ g_out,
    int t0, int nt)
{
    __shared__ __attribute__((aligned(16))) short hbf[2 * 16 * 168];
    __shared__ float hs2[16 * 132];
    __shared__ float GHb[16 * 390];
    __shared__ float bihS[387];
    __shared__ float bhhS[387];

    const int tid  = threadIdx.x;
    const int l    = tid & 63;
    const int w    = tid >> 6;        // wave 0..15
    const int b0   = blockIdx.x * 16;
    const int bcol = l & 15;
    const int krow = l >> 4;
    const bool has1 = (w < 9);        // second tile jt = 16+w

    if (tid < 387) { bihS[tid] = bih[tid]; bhhS[tid] = bhh[tid]; }
    for (int e = tid; e < 2688; e += 1024) ((unsigned int*)hbf)[e] = 0u;
    if (t0 == 0) {
        for (int e = tid; e < 16 * 132; e += 1024) hs2[e] = 0.f;
        __syncthreads();
    } else {
        for (int e = tid; e < 16 * 132; e += 1024) hs2[e] = hstate[(size_t)b0 * 132 + e];
        __syncthreads();
        for (int e = tid; e < 2064; e += 1024) {
            int r = e & 15, j = e >> 4;
            float v = hs2[r * 132 + j];
            unsigned short hb = f2bf(v);
            hbf[r * 168 + j]        = (short)hb;
            hbf[2688 + r * 168 + j] = (short)f2bf(v - bf2f(hb));
        }
        __syncthreads();
    }

    const bf16x8* at = (const bf16x8*)awhh;

    #define GATE(E, PGA, PGB, PGC) { \
        int r_ = (E) & 15, j_ = (E) >> 4; \
        float pr_  = (PGA) + GHb[r_ * 390 + j_]       + bihS[j_]       + bhhS[j_]; \
        float pz_  = (PGB) + GHb[r_ * 390 + 129 + j_] + bihS[129 + j_] + bhhS[129 + j_]; \
        float gin_ = (PGC) + bihS[258 + j_]; \
        float ghn_ = GHb[r_ * 390 + 258 + j_] + bhhS[258 + j_]; \
        float rg_ = fast_sigmoid(pr_); \
        float zg_ = fast_sigmoid(pz_); \
        float nn_ = fast_tanh(gin_ + rg_ * ghn_); \
        float hn_ = (1.f - zg_) * nn_ + zg_ * hs2[r_ * 132 + j_]; \
        hs2[r_ * 132 + j_] = hn_; \
        unsigned short hb_ = f2bf(hn_); \
        hbf[r_ * 168 + j_]        = (short)hb_; \
        hbf[2688 + r_ * 168 + j_] = (short)f2bf(hn_ - bf2f(hb_)); }

    for (int tt = 0; tt < nt; ++tt) {
        const float* gib = gic + (size_t)tt * 387 * 4096 + b0;
        float pa0, pb0, pc0, pa1, pb1, pc1;
        {
            int r = tid & 15, j = tid >> 4;
            pa0 = gib[(size_t)j * 4096 + r];
            pb0 = gib[(size_t)(129 + j) * 4096 + r];
            pc0 = gib[(size_t)(258 + j) * 4096 + r];
            int e = tid + 1024; r = e & 15; j = e >> 4;   // e <= 2047 < 2064
            pa1 = gib[(size_t)j * 4096 + r];
            pb1 = gib[(size_t)(129 + j) * 4096 + r];
            pc1 = gib[(size_t)(258 + j) * 4096 + r];
        }

        f32x4 acc0 = {0.f,0.f,0.f,0.f}, acc1 = {0.f,0.f,0.f,0.f};
        #pragma unroll
        for (int kt = 0; kt < 5; ++kt) {
            bf16x8 bh = *(const bf16x8*)(hbf + bcol * 168 + kt * 32 + krow * 8);
            bf16x8 bl = *(const bf16x8*)(hbf + 2688 + bcol * 168 + kt * 32 + krow * 8);
            {
                int fb = ((w * 5 + kt) * 2) * 64 + l;
                bf16x8 Ah = at[fb], Al = at[fb + 64];
                acc0 = __builtin_amdgcn_mfma_f32_16x16x32_bf16(Al, bh, acc0, 0, 0, 0);
                acc0 = __builtin_amdgcn_mfma_f32_16x16x32_bf16(Ah, bl, acc0, 0, 0, 0);
                acc0 = __builtin_amdgcn_mfma_f32_16x16x32_bf16(Ah, bh, acc0, 0, 0, 0);
            }
            if (has1) {
                int fb = (((16 + w) * 5 + kt) * 2) * 64 + l;
                bf16x8 Ah = at[fb], Al = at[fb + 64];
                acc1 = __builtin_amdgcn_mfma_f32_16x16x32_bf16(Al, bh, acc1, 0, 0, 0);
                acc1 = __builtin_amdgcn_mfma_f32_16x16x32_bf16(Ah, bl, acc1, 0, 0, 0);
                acc1 = __builtin_amdgcn_mfma_f32_16x16x32_bf16(Ah, bh, acc1, 0, 0, 0);
            }
        }
        {
            int rb = bcol * 390;
            int j0 = w * 16 + krow * 4;          // jt = w: j <= 255, always valid
            GHb[rb + j0 + 0] = acc0[0];
            GHb[rb + j0 + 1] = acc0[1];
            GHb[rb + j0 + 2] = acc0[2];
            GHb[rb + j0 + 3] = acc0[3];
            if (has1) {
                if (w < 8) {                      // jt 16..23: j <= 383, valid
                    int j1 = (16 + w) * 16 + krow * 4;
                    GHb[rb + j1 + 0] = acc1[0];
                    GHb[rb + j1 + 1] = acc1[1];
                    GHb[rb + j1 + 2] = acc1[2];
                    GHb[rb + j1 + 3] = acc1[3];
                } else if (krow == 0) {           // jt 24: only j = 384..386
                    GHb[rb + 384] = acc1[0];
                    GHb[rb + 385] = acc1[1];
                    GHb[rb + 386] = acc1[2];
                }
            }
        }
        __syncthreads();

        GATE(tid,        pa0, pb0, pc0)
        GATE(tid + 1024, pa1, pb1, pc1)
        if (tid < 16) {
            float ta = gib[(size_t)128 * 4096 + tid];
            float tb = gib[(size_t)257 * 4096 + tid];
            float tc = gib[(size_t)386 * 4096 + tid];
            GATE(2048 + tid, ta, tb, tc)
        }
        __syncthreads();
    }

    for (int e = tid; e < 16 * 132; e += 1024) hstate[(size_t)b0 * 132 + e] = hs2[e];
    if (t0 + nt >= 60) {
        for (int e = tid; e < 2064; e += 1024) {
            int r = e & 15, j = e >> 4;
            float v = hs2[r * 132 + j];
            g_out[(size_t)(b0 + r) * 129 + j] = (v >= 0.f) ? v : 0.01f * v;
        }
        if (tid < 16) {
            float v = hs2[tid * 132 + 128];
            g_out[(size_t)(b0 + tid) * 129 + 128] = (v >= 0.f) ? v : 0.01f * v;
        }
    }
    #undef GATE
}

// ---------------------------------------------------------------------------
// Head: feat=[g,w] (258) -> mu, log_std -> sample, tanh, log_pi, normalize.
// ---------------------------------------------------------------------------
__global__ __launch_bounds__(256) void head_kernel(
    const float* __restrict__ gbuf, const float* __restrict__ wvec,
    const float* __restrict__ eps,
    const float* __restrict__ muwp, const float* __restrict__ lswp,
    const float* __restrict__ mub,  const float* __restrict__ lsb,
    float* __restrict__ out)
{
    __shared__ __attribute__((aligned(16))) float feat[16 * 260];
    __shared__ float PA[16 * 130];
    __shared__ float TERM[16 * 130];
    __shared__ float ROWSUM[16];
    __shared__ float ROWLOG[16];

    const int tid = threadIdx.x;
    const int b0  = blockIdx.x * 16;

    for (int i = tid; i < 16 * 260; i += 256) {
        int r = i / 260;
        int k = i - r * 260;
        float v = 0.f;
        if (k < 129)       v = gbuf[(size_t)(b0 + r) * 129 + k];
        else if (k < 258)  v = wvec[(size_t)(b0 + r) * 129 + (k - 129)];
        feat[i] = v;
    }
    __syncthreads();

    for (int idx = tid; idx < 16 * 129; idx += 256) {
        int r = idx & 15;
        int j = idx >> 4;
        const float4* fv = (const float4*)(feat + r * 260);
        const float4* mw = (const float4*)(muwp + (size_t)j * 260);
        const float4* lw = (const float4*)(lswp + (size_t)j * 260);
        float am = 0.f, al = 0.f;
        for (int k = 0; k < 65; ++k) {
            float4 f = fv[k];
            float4 m = mw[k];
            float4 l = lw[k];
            am += f.x * m.x + f.y * m.y + f.z * m.z + f.w * m.w;
            al += f.x * l.x + f.y * l.y + f.z * l.z + f.w * l.w;
        }
        float mu = am + mub[j];
        float ls = fminf(fmaxf(al + lsb[j], -20.f), 2.f);
        float sd = __expf(ls);
        float e  = eps[(size_t)(b0 + r) * 129 + j];
        float xv = mu + sd * e;
        float pa = fast_tanh(xv);
        float tt = (xv - mu) / sd;
        float term = -0.5f * tt * tt - ls - 0.91893853320467274f
                     - __logf(1.f - pa * pa + 1e-6f);
        PA[r * 130 + j]   = pa;
        TERM[r * 130 + j] = term;
    }
    __syncthreads();

    {
        int r = tid >> 4;
        int i = tid & 15;
        float sp = 0.f, st = 0.f;
        for (int j = i; j < 129; j += 16) {
            sp += PA[r * 130 + j];
            st += TERM[r * 130 + j];
        }
        for (int off = 8; off > 0; off >>= 1) {
            sp += __shfl_down(sp, off, 16);
            st += __shfl_down(st, off, 16);
        }
        if (i == 0) { ROWSUM[r] = sp + 129.f; ROWLOG[r] = st; }
    }
    __syncthreads();

    for (int idx = tid; idx < 16 * 129; idx += 256) {
        int r = idx & 15;
        int j = idx >> 4;
        out[(size_t)(b0 + r) * 129 + j] = (PA[r * 130 + j] + 1.f) / ROWSUM[r];
    }
    if (tid < 16)
        out[(size_t)4096 * 129 + b0 + tid] = ROWLOG[tid];
}

// ---------------------------------------------------------------------------
extern "C" void kernel_launch(void* const* d_in, const int* in_sizes, int n_in,
                              void* d_out, int out_size, void* d_ws, size_t ws_size,
                              hipStream_t stream)
{
    const float* x   = (const float*)d_in[0];
    const float* wv  = (const float*)d_in[1];
    const float* eps = (const float*)d_in[2];
    const float* c1w = (const float*)d_in[3];
    const float* c1b = (const float*)d_in[4];
    const float* c2w = (const float*)d_in[5];
    const float* c2b = (const float*)d_in[6];
    const float* Wih = (const float*)d_in[7];
    const float* Whh = (const float*)d_in[8];
    const float* bih = (const float*)d_in[9];
    const float* bhh = (const float*)d_in[10];
    const float* muw = (const float*)d_in[11];
    const float* mub = (const float*)d_in[12];
    const float* lsw = (const float*)d_in[13];
    const float* lsb = (const float*)d_in[14];

    float* ws     = (float*)d_ws;
    float* seq    = ws + SEQ_OFF;
    float* g      = ws + G_OFF;
    float* hstate = ws + HST_OFF;
    const short* awhh = (const short*)(ws + AWHH_OFF);
    const short* awih = (const short*)(ws + AWIH_OFF);
    float* muwp   = ws + MUWP_OFF;
    float* lswp   = ws + LSWP_OFF;
    float* outp   = (float*)d_out;

    // chunk size over t: seqbf (655360 fl/t) + gic (1585152 fl/t)
    const long per_t = (long)PER_T_GIC + PER_T_SBF;
    long avail = (long)(ws_size / 4) - (long)BUF_OFF;
    int CT = 60;
    if (avail < 60 * per_t) {
        CT = (int)(avail / per_t);
        if (CT < 1) CT = 1;
        if (CT > 60) CT = 60;
    }
    float* sbff = ws + BUF_OFF;                       // seqbf region (CT*655360 floats)
    float* gic  = ws + BUF_OFF + (size_t)CT * PER_T_SBF;

    const int prep_elems = 25 * 5 * 2 * 512 + 25 * 4 * 2 * 512 + 2 * (129 * 260);
    prep_pad<<<(prep_elems + 255) / 256, 256, 0, stream>>>(Whh, Wih, muw, lsw, ws);
    conv_fused<<<dim3(6, BTOT), 256, 0, stream>>>(x, c1w, c1b, c2w, c2b, seq);

    for (int t0 = 0; t0 < 60; t0 += CT) {
        int nt = 60 - t0; if (nt > CT) nt = CT;
        long nb = ((long)nt * 327680 + 255) / 256;
        seq2bf<<<(int)nb, 256, 0, stream>>>(seq, (unsigned long long*)sbff, t0, nt);
        gi_mfma<<<dim3(32, 25), 512, 0, stream>>>((const short*)sbff, awih, gic, nt);
        gru_mfma<<<256, 1024, 0, stream>>>(gic, awhh, bih, bhh, hstate, g, t0, nt);
    }
    head_kernel<<<BTOT / 16, 256, 0, stream>>>(g, wv, eps, muwp, lswp, mub, lsb, outp);
}

// Round 25
// 1320.479 us; speedup vs baseline: 1.1455x; 1.1455x over previous
//
#include <hip/hip_runtime.h>
#include <math.h>

// Problem constants
#define BTOT   4096
#define CIN    3
#define TIN    64
#define SIN    128

// ws layout (float offsets)  [R25: seq fp32 eliminated; sbf is full 60-t]
#define G_OFF      0                             // [4096][129]
#define HST_OFF    (G_OFF + 4096*129)            // [4096][132]
#define AWHH_OFF   (HST_OFF + 4096*132)          // [25][5][2][64][8] bf16 Whh frags
#define AWIH_OFF   (AWHH_OFF + 64000)            // [25][4][2][64][8] bf16 Wih frags
#define MUWP_OFF   (AWIH_OFF + 51200)            // [129][260]
#define LSWP_OFF   (MUWP_OFF + 129*260)          // [129][260]
#define SBF_OFF    (LSWP_OFF + 129*260)          // [60][32][10240 ull] = 60*655360 floats
#define GIC_OFF    (SBF_OFF + 60*655360)         // [CT][387][4096]

// per-t sizes
#define PER_T_GIC   (387 * 4096)
#define SBF_T_SH    1310720                      // shorts per t

typedef __attribute__((ext_vector_type(8))) short bf16x8;
typedef __attribute__((ext_vector_type(4))) float f32x4;

// Inline transcendentals (no libm calls in hot loops)
__device__ __forceinline__ float fast_tanh(float x) {
    float ax = fabsf(x);
    float t  = __expf(-2.f * ax);
    float r  = (1.f - t) / (1.f + t);
    return copysignf(r, x);
}
__device__ __forceinline__ float fast_sigmoid(float x) {
    return 1.f / (1.f + __expf(-x));
}
// bf16 round-to-nearest-even helpers (bit ops only)
__device__ __forceinline__ unsigned short f2bf(float x) {
    unsigned int u = __float_as_uint(x);
    unsigned int r = u + 0x7FFFu + ((u >> 16) & 1u);
    return (unsigned short)(r >> 16);
}
__device__ __forceinline__ float bf2f(unsigned short b) {
    return __uint_as_float(((unsigned int)b) << 16);
}

// ---------------------------------------------------------------------------
// Prep: bf16 hi/lo fragment tables for Whh (5 k-tiles) and Wih (4 k-tiles),
// plus fc weight padding. (Passing R18-R24.)
// ---------------------------------------------------------------------------
__global__ __launch_bounds__(256) void prep_pad(
    const float* __restrict__ Whh, const float* __restrict__ Wih,
    const float* __restrict__ muw, const float* __restrict__ lsw,
    float* __restrict__ ws)
{
    int idx = blockIdx.x * 256 + threadIdx.x;
    const int NHH = 25 * 5 * 2 * 512;   // 128000 shorts
    const int NIA = 25 * 4 * 2 * 512;   // 102400 shorts
    const int N2  = 129 * 260;
    if (idx < NHH) {
        int a      = idx;
        int frag   = a >> 9;
        int within = a & 511;
        int l      = within >> 3;
        int c      = within & 7;
        int half   = frag & 1;
        int q      = frag >> 1;
        int kt     = q % 5;
        int jt     = q / 5;
        int j      = jt * 16 + (l & 15);
        int k      = kt * 32 + (l >> 4) * 8 + c;
        float v    = (j < 387 && k < 129) ? Whh[(size_t)j * 129 + k] : 0.f;
        unsigned short hb = f2bf(v);
        ((short*)(ws + AWHH_OFF))[a] = (short)((half == 0) ? hb : f2bf(v - bf2f(hb)));
    } else if (idx < NHH + NIA) {
        int a      = idx - NHH;
        int frag   = a >> 9;
        int within = a & 511;
        int l      = within >> 3;
        int c      = within & 7;
        int half   = frag & 1;
        int q      = frag >> 1;
        int kt     = q & 3;
        int jt     = q >> 2;
        int j      = jt * 16 + (l & 15);
        int k      = kt * 32 + (l >> 4) * 8 + c;
        float v    = (j < 387 && k < 124) ? Wih[(size_t)j * 124 + k] : 0.f;
        unsigned short hb = f2bf(v);
        ((short*)(ws + AWIH_OFF))[a] = (short)((half == 0) ? hb : f2bf(v - bf2f(hb)));
    } else if (idx < NHH + NIA + N2) {
        int i = idx - NHH - NIA; int j = i / 260, k = i - j * 260;
        ws[MUWP_OFF + i] = (k < 258) ? muw[j * 258 + k] : 0.f;
    } else if (idx < NHH + NIA + 2 * N2) {
        int i = idx - NHH - NIA - N2; int j = i / 260, k = i - j * 260;
        ws[LSWP_OFF + i] = (k < 258) ? lsw[j * 258 + k] : 0.f;
    }
}

// ---------------------------------------------------------------------------
// sbf_padzero (R25): zero the ONLY pad region gi actually reads: k=124..127
// (frag 6,7 = kt3 hi/lo, ksub=3, c0=4) for every (t, chunk, bi).
// 491520 half-ull stores. (ksub==4 slots are never read: gi's ksub = l>>4 <= 3.)
// ---------------------------------------------------------------------------
__global__ __launch_bounds__(256) void sbf_padzero(short* __restrict__ sbf)
{
    int a = blockIdx.x * 256 + threadIdx.x;
    if (a >= 60 * 32 * 128 * 2) return;
    int half  = a & 1;
    int bi    = (a >> 1) & 127;
    int chunk = (a >> 8) & 31;
    int t     = a >> 13;
    size_t s = (size_t)t * SBF_T_SH + (size_t)chunk * 40960
             + (size_t)(6 + half) * 5120 + (size_t)bi * 40 + 3 * 8 + 4;
    *(unsigned long long*)(sbf + s) = 0ull;
}

// ---------------------------------------------------------------------------
// conv_fused v5 (R25): conv2 writes seqbf (bf16 hi/lo frag layout) DIRECTLY
// -- seq fp32 and the seq2bf kernel are eliminated. Each conv2 task's 4
// consecutive k-values are exactly one hi-ull + one lo-ull in the layout
// short_idx = t*SBF_T_SH + chunk*40960 + (kt*2+half)*5120 + bi*40 + ksub*8 + c0.
// conv1 unchanged (3-set rolling window; R22 proved 4-set spills).
// ---------------------------------------------------------------------------
#define RACC(F4_, F2_, W0_, W1_, W2_) \
    acc0 += (F4_).x*(W0_) + (F4_).y*(W1_) + (F4_).z*(W2_); \
    acc1 += (F4_).y*(W0_) + (F4_).z*(W1_) + (F4_).w*(W2_); \
    acc2 += (F4_).z*(W0_) + (F4_).w*(W1_) + (F2_).x*(W2_); \
    acc3 += (F4_).w*(W0_) + (F2_).x*(W1_) + (F2_).y*(W2_);

#define LDSET(S, TR_) { \
    S##0_4 = *(const float4*)(xc0 + (TR_) * 128 + s0); \
    S##0_2 = *(const float2*)(xc0 + (TR_) * 128 + f2c); \
    S##1_4 = *(const float4*)(xc1 + (TR_) * 128 + s0); \
    S##1_2 = *(const float2*)(xc1 + (TR_) * 128 + f2c); \
    S##2_4 = *(const float4*)(xc2 + (TR_) * 128 + s0); \
    S##2_2 = *(const float2*)(xc2 + (TR_) * 128 + f2c); }

#define C1STEP(SA, SB, SC, TQ_) { \
    float acc0 = bo, acc1 = bo, acc2 = bo, acc3 = bo; \
    RACC(SA##0_4, SA##0_2, w000, w001, w002) \
    RACC(SA##1_4, SA##1_2, w100, w101, w102) \
    RACC(SA##2_4, SA##2_2, w200, w201, w202) \
    RACC(SB##0_4, SB##0_2, w010, w011, w012) \
    RACC(SB##1_4, SB##1_2, w110, w111, w112) \
    RACC(SB##2_4, SB##2_2, w210, w211, w212) \
    RACC(SC##0_4, SC##0_2, w020, w021, w022) \
    RACC(SC##1_4, SC##1_2, w120, w121, w122) \
    RACC(SC##2_4, SC##2_2, w220, w221, w222) \
    float4 r_; \
    r_.x = (acc0 >= 0.f) ? acc0 : 0.01f * acc0; \
    r_.y = (acc1 >= 0.f) ? acc1 : 0.01f * acc1; \
    r_.z = (acc2 >= 0.f) ? acc2 : 0.01f * acc2; \
    r_.w = (acc3 >= 0.f) ? acc3 : 0.01f * acc3; \
    *(float4*)(h1t + (o * 12 + (TQ_)) * 128 + s0) = r_; }

#define C2SEG(o_, kt_, W0_, W1_, W2_) { \
    const float* rp_ = h1t + ((o_) * 12 + tq + (kt_)) * 128 + s0; \
    float4 v4_ = *(const float4*)rp_; \
    float2 v2_ = *(const float2*)(rp_ + 4); \
    acc0 += v4_.x*(W0_) + v4_.y*(W1_) + v4_.z*(W2_); \
    acc1 += v4_.y*(W0_) + v4_.z*(W1_) + v4_.w*(W2_); \
    acc2 += v4_.z*(W0_) + v4_.w*(W1_) + v2_.x*(W2_); \
    acc3 += v4_.w*(W0_) + v2_.x*(W1_) + v2_.y*(W2_); }

__global__ __launch_bounds__(256) void conv_fused(
    const float* __restrict__ x,
    const float* __restrict__ w1, const float* __restrict__ b1,
    const float* __restrict__ w2, const float* __restrict__ b2,
    short* __restrict__ sbf)
{
    __shared__ __attribute__((aligned(16))) float h1t[6 * 12 * 128];
    __shared__ float w1s[162];
    __shared__ float w2s[54];
    __shared__ float b1s[6];
    __shared__ float b2s;

    const int tid  = threadIdx.x;
    const int tile = blockIdx.x;   // 0..5
    const int bb   = blockIdx.y;   // batch
    const int T0   = tile * 10;

    if (tid < 162)                  w1s[tid] = w1[tid];
    if (tid >= 192 && tid < 246)    w2s[tid - 192] = w2[tid - 192];
    if (tid >= 248 && tid < 254)    b1s[tid - 248] = b1[tid - 248];
    if (tid == 255)                 b2s = b2[0];
    __syncthreads();

    if (tid < 192) {
        const int o   = tid >> 5;
        const int s0  = (tid & 31) * 4;
        const int f2c = (s0 < 124) ? (s0 + 4) : 122;   // clamp: junk cols only
        const float* wb = w1s + o * 27;
        float w000 = wb[0],  w001 = wb[1],  w002 = wb[2];
        float w010 = wb[3],  w011 = wb[4],  w012 = wb[5];
        float w020 = wb[6],  w021 = wb[7],  w022 = wb[8];
        float w100 = wb[9],  w101 = wb[10], w102 = wb[11];
        float w110 = wb[12], w111 = wb[13], w112 = wb[14];
        float w120 = wb[15], w121 = wb[16], w122 = wb[17];
        float w200 = wb[18], w201 = wb[19], w202 = wb[20];
        float w210 = wb[21], w211 = wb[22], w212 = wb[23];
        float w220 = wb[24], w221 = wb[25], w222 = wb[26];
        float bo = b1s[o];

        const float* xc0 = x + (size_t)bb * (3 * 64 * 128) + (size_t)T0 * 128;
        const float* xc1 = xc0 + 64 * 128;
        const float* xc2 = xc0 + 2 * 64 * 128;

        float4 A0_4, A1_4, A2_4, B0_4, B1_4, B2_4, C0_4, C1_4, C2_4;
        float2 A0_2, A1_2, A2_2, B0_2, B1_2, B2_2, C0_2, C1_2, C2_2;

        LDSET(A, 0)
        LDSET(B, 1)
        LDSET(C, 2)  C1STEP(A, B, C, 0)
        LDSET(A, 3)  C1STEP(B, C, A, 1)
        LDSET(B, 4)  C1STEP(C, A, B, 2)
        LDSET(C, 5)  C1STEP(A, B, C, 3)
        LDSET(A, 6)  C1STEP(B, C, A, 4)
        LDSET(B, 7)  C1STEP(C, A, B, 5)
        LDSET(C, 8)  C1STEP(A, B, C, 6)
        LDSET(A, 9)  C1STEP(B, C, A, 7)
        LDSET(B, 10) C1STEP(C, A, B, 8)
        LDSET(C, 11) C1STEP(A, B, C, 9)
        LDSET(A, 12) C1STEP(B, C, A, 10)
        LDSET(B, 13) C1STEP(C, A, B, 11)
    }
    __syncthreads();

    {
        float u000 = w2s[0],  u001 = w2s[1],  u002 = w2s[2];
        float u010 = w2s[3],  u011 = w2s[4],  u012 = w2s[5];
        float u020 = w2s[6],  u021 = w2s[7],  u022 = w2s[8];
        float u100 = w2s[9],  u101 = w2s[10], u102 = w2s[11];
        float u110 = w2s[12], u111 = w2s[13], u112 = w2s[14];
        float u120 = w2s[15], u121 = w2s[16], u122 = w2s[17];
        float u200 = w2s[18], u201 = w2s[19], u202 = w2s[20];
        float u210 = w2s[21], u211 = w2s[22], u212 = w2s[23];
        float u220 = w2s[24], u221 = w2s[25], u222 = w2s[26];
        float u300 = w2s[27], u301 = w2s[28], u302 = w2s[29];
        float u310 = w2s[30], u311 = w2s[31], u312 = w2s[32];
        float u320 = w2s[33], u321 = w2s[34], u322 = w2s[35];
        float u400 = w2s[36], u401 = w2s[37], u402 = w2s[38];
        float u410 = w2s[39], u411 = w2s[40], u412 = w2s[41];
        float u420 = w2s[42], u421 = w2s[43], u422 = w2s[44];
        float u500 = w2s[45], u501 = w2s[46], u502 = w2s[47];
        float u510 = w2s[48], u511 = w2s[49], u512 = w2s[50];
        float u520 = w2s[51], u521 = w2s[52], u522 = w2s[53];
        float bo2 = b2s;
        const int chunk = bb >> 7;
        const int bi    = bb & 127;
        for (int idx = tid; idx < 310; idx += 256) {
            const int tq = idx / 31;
            const int s0 = (idx - tq * 31) * 4;
            float acc0 = bo2, acc1 = bo2, acc2 = bo2, acc3 = bo2;
            C2SEG(0, 0, u000, u001, u002)
            C2SEG(0, 1, u010, u011, u012)
            C2SEG(0, 2, u020, u021, u022)
            C2SEG(1, 0, u100, u101, u102)
            C2SEG(1, 1, u110, u111, u112)
            C2SEG(1, 2, u120, u121, u122)
            C2SEG(2, 0, u200, u201, u202)
            C2SEG(2, 1, u210, u211, u212)
            C2SEG(2, 2, u220, u221, u222)
            C2SEG(3, 0, u300, u301, u302)
            C2SEG(3, 1, u310, u311, u312)
            C2SEG(3, 2, u320, u321, u322)
            C2SEG(4, 0, u400, u401, u402)
            C2SEG(4, 1, u410, u411, u412)
            C2SEG(4, 2, u420, u421, u422)
            C2SEG(5, 0, u500, u501, u502)
            C2SEG(5, 1, u510, u511, u512)
            C2SEG(5, 2, u520, u521, u522)
            float r0 = (acc0 >= 0.f) ? acc0 : 0.01f * acc0;
            float r1 = (acc1 >= 0.f) ? acc1 : 0.01f * acc1;
            float r2 = (acc2 >= 0.f) ? acc2 : 0.01f * acc2;
            float r3 = (acc3 >= 0.f) ? acc3 : 0.01f * acc3;
            // pack hi/lo bf16 and store directly into seqbf layout
            unsigned short H0 = f2bf(r0), H1 = f2bf(r1), H2 = f2bf(r2), H3 = f2bf(r3);
            unsigned short Q0 = f2bf(r0 - bf2f(H0));
            unsigned short Q1 = f2bf(r1 - bf2f(H1));
            unsigned short Q2 = f2bf(r2 - bf2f(H2));
            unsigned short Q3 = f2bf(r3 - bf2f(H3));
            unsigned long long hp = (unsigned long long)H0 | ((unsigned long long)H1 << 16)
                                  | ((unsigned long long)H2 << 32) | ((unsigned long long)H3 << 48);
            unsigned long long lp = (unsigned long long)Q0 | ((unsigned long long)Q1 << 16)
                                  | ((unsigned long long)Q2 << 32) | ((unsigned long long)Q3 << 48);
            const int kt   = s0 >> 5;
            const int ksub = (s0 >> 3) & 3;
            const int c0   = s0 & 7;
            size_t sb = (size_t)(T0 + tq) * SBF_T_SH + (size_t)chunk * 40960
                      + (size_t)(kt * 2) * 5120 + (size_t)bi * 40 + ksub * 8 + c0;
            *(unsigned long long*)(sbf + sb)        = hp;
            *(unsigned long long*)(sbf + sb + 5120) = lp;
        }
    }
}

// ---------------------------------------------------------------------------
// gi via MFMA v3 (R25): absolute-t indexing into the full seqbf.
// ---------------------------------------------------------------------------
__global__ __launch_bounds__(512) void gi_mfma(
    const short* __restrict__ sbf, const short* __restrict__ awih,
    float* __restrict__ gic, int t0, int nt)
{
    const int tid = threadIdx.x;
    const int l   = tid & 63;
    const int w   = tid >> 6;          // n-tile 0..7
    const int jt  = blockIdx.y;        // 0..24
    const int bx  = blockIdx.x;
    const int b0  = bx * 128;

    const bf16x8* at = (const bf16x8*)awih;
    const int abase = jt * 8 * 64 + l;
    bf16x8 Ah0 = at[abase + 0 * 128];
    bf16x8 Al0 = at[abase + 0 * 128 + 64];
    bf16x8 Ah1 = at[abase + 1 * 128];
    bf16x8 Al1 = at[abase + 1 * 128 + 64];
    bf16x8 Ah2 = at[abase + 2 * 128];
    bf16x8 Al2 = at[abase + 2 * 128 + 64];
    bf16x8 Ah3 = at[abase + 3 * 128];
    bf16x8 Al3 = at[abase + 3 * 128 + 64];

    const int bn   = w * 16 + (l & 15);
    const int ksub = l >> 4;
    const int off0 = bx * 40960 + (bn * 5 + ksub) * 8;
    const int row0 = ksub * 4;

    for (int tt = 0; tt < nt; ++tt) {
        const short* sb = sbf + (size_t)(t0 + tt) * SBF_T_SH + off0;
        f32x4 acc = {0.f, 0.f, 0.f, 0.f};
        #define GI_KT(KT, AH, AL) { \
            bf16x8 bh = *(const bf16x8*)(sb + ((KT) * 2 + 0) * 5120); \
            bf16x8 bl = *(const bf16x8*)(sb + ((KT) * 2 + 1) * 5120); \
            acc = __builtin_amdgcn_mfma_f32_16x16x32_bf16(AL, bh, acc, 0, 0, 0); \
            acc = __builtin_amdgcn_mfma_f32_16x16x32_bf16(AH, bl, acc, 0, 0, 0); \
            acc = __builtin_amdgcn_mfma_f32_16x16x32_bf16(AH, bh, acc, 0, 0, 0); }
        GI_KT(0, Ah0, Al0)
        GI_KT(1, Ah1, Al1)
        GI_KT(2, Ah2, Al2)
        GI_KT(3, Ah3, Al3)
        #undef GI_KT

        float* gt = gic + (size_t)tt * 387 * 4096;
        #pragma unroll
        for (int i = 0; i < 4; ++i) {
            int j = jt * 16 + row0 + i;
            if (j < 387)
                gt[(size_t)j * 4096 + b0 + bn] = acc[i];
        }
    }
}

// ---------------------------------------------------------------------------
// GRU recurrence via MFMA v2 — passing R24 (unchanged).
// ---------------------------------------------------------------------------
__global__ __launch_bounds__(1024) void gru_mfma(
    const float* __restrict__ gic, const short* __restrict__ awhh,
    const float* __restrict__ bih, const float* __restrict__ bhh,
    float* __restrict__ hstate, float* __restrict__ g_out,
    int t0, int nt)
{
    __shared__ __attribute__((aligned(16))) short hbf[2 * 16 * 168];
    __shared__ float hs2[16 * 132];
    __shared__ float GHb[16 * 390];
    __shared__ float bihS[387];
    __shared__ float bhhS[387];

    const int tid  = threadIdx.x;
    const int l    = tid & 63;
    const int w    = tid >> 6;        // wave 0..15
    const int b0   = blockIdx.x * 16;
    const int bcol = l & 15;
    const int krow = l >> 4;
    const bool has1 = (w < 9);        // second tile jt = 16+w

    if (tid < 387) { bihS[tid] = bih[tid]; bhhS[tid] = bhh[tid]; }
    for (int e = tid; e < 2688; e += 1024) ((unsigned int*)hbf)[e] = 0u;
    if (t0 == 0) {
        for (int e = tid; e < 16 * 132; e += 1024) hs2[e] = 0.f;
        __syncthreads();
    } else {
        for (int e = tid; e < 16 * 132; e += 1024) hs2[e] = hstate[(size_t)b0 * 132 + e];
        __syncthreads();
        for (int e = tid; e < 2064; e += 1024) {
            int r = e & 15, j = e >> 4;
            float v = hs2[r * 132 + j];
            unsigned short hb = f2bf(v);
            hbf[r * 168 + j]        = (short)hb;
            hbf[2688 + r * 168 + j] = (short)f2bf(v - bf2f(hb));
        }
        __syncthreads();
    }

    const bf16x8* at = (const bf16x8*)awhh;

    #define GATE(E, PGA, PGB, PGC) { \
        int r_ = (E) & 15, j_ = (E) >> 4; \
        float pr_  = (PGA) + GHb[r_ * 390 + j_]       + bihS[j_]       + bhhS[j_]; \
        float pz_  = (PGB) + GHb[r_ * 390 + 129 + j_] + bihS[129 + j_] + bhhS[129 + j_]; \
        float gin_ = (PGC) + bihS[258 + j_]; \
        float ghn_ = GHb[r_ * 390 + 258 + j_] + bhhS[258 + j_]; \
        float rg_ = fast_sigmoid(pr_); \
        float zg_ = fast_sigmoid(pz_); \
        float nn_ = fast_tanh(gin_ + rg_ * ghn_); \
        float hn_ = (1.f - zg_) * nn_ + zg_ * hs2[r_ * 132 + j_]; \
        hs2[r_ * 132 + j_] = hn_; \
        unsigned short hb_ = f2bf(hn_); \
        hbf[r_ * 168 + j_]        = (short)hb_; \
        hbf[2688 + r_ * 168 + j_] = (short)f2bf(hn_ - bf2f(hb_)); }

    for (int tt = 0; tt < nt; ++tt) {
        const float* gib = gic + (size_t)tt * 387 * 4096 + b0;
        float pa0, pb0, pc0, pa1, pb1, pc1;
        {
            int r = tid & 15, j = tid >> 4;
            pa0 = gib[(size_t)j * 4096 + r];
            pb0 = gib[(size_t)(129 + j) * 4096 + r];
            pc0 = gib[(size_t)(258 + j) * 4096 + r];
            int e = tid + 1024; r = e & 15; j = e >> 4;   // e <= 2047 < 2064
            pa1 = gib[(size_t)j * 4096 + r];
            pb1 = gib[(size_t)(129 + j) * 4096 + r];
            pc1 = gib[(size_t)(258 + j) * 4096 + r];
        }

        f32x4 acc0 = {0.f,0.f,0.f,0.f}, acc1 = {0.f,0.f,0.f,0.f};
        #pragma unroll
        for (int kt = 0; kt < 5; ++kt) {
            bf16x8 bh = *(const bf16x8*)(hbf + bcol * 168 + kt * 32 + krow * 8);
            bf16x8 bl = *(const bf16x8*)(hbf + 2688 + bcol * 168 + kt * 32 + krow * 8);
            {
                int fb = ((w * 5 + kt) * 2) * 64 + l;
                bf16x8 Ah = at[fb], Al = at[fb + 64];
                acc0 = __builtin_amdgcn_mfma_f32_16x16x32_bf16(Al, bh, acc0, 0, 0, 0);
                acc0 = __builtin_amdgcn_mfma_f32_16x16x32_bf16(Ah, bl, acc0, 0, 0, 0);
                acc0 = __builtin_amdgcn_mfma_f32_16x16x32_bf16(Ah, bh, acc0, 0, 0, 0);
            }
            if (has1) {
                int fb = (((16 + w) * 5 + kt) * 2) * 64 + l;
                bf16x8 Ah = at[fb], Al = at[fb + 64];
                acc1 = __builtin_amdgcn_mfma_f32_16x16x32_bf16(Al, bh, acc1, 0, 0, 0);
                acc1 = __builtin_amdgcn_mfma_f32_16x16x32_bf16(Ah, bl, acc1, 0, 0, 0);
                acc1 = __builtin_amdgcn_mfma_f32_16x16x32_bf16(Ah, bh, acc1, 0, 0, 0);
            }
        }
        {
            int rb = bcol * 390;
            int j0 = w * 16 + krow * 4;          // jt = w: j <= 255, always valid
            GHb[rb + j0 + 0] = acc0[0];
            GHb[rb + j0 + 1] = acc0[1];
            GHb[rb + j0 + 2] = acc0[2];
            GHb[rb + j0 + 3] = acc0[3];
            if (has1) {
                if (w < 8) {                      // jt 16..23: j <= 383, valid
                    int j1 = (16 + w) * 16 + krow * 4;
                    GHb[rb + j1 + 0] = acc1[0];
                    GHb[rb + j1 + 1] = acc1[1];
                    GHb[rb + j1 + 2] = acc1[2];
                    GHb[rb + j1 + 3] = acc1[3];
                } else if (krow == 0) {           // jt 24: only j = 384..386
                    GHb[rb + 384] = acc1[0];
                    GHb[rb + 385] = acc1[1];
                    GHb[rb + 386] = acc1[2];
                }
            }
        }
        __syncthreads();

        GATE(tid,        pa0, pb0, pc0)
        GATE(tid + 1024, pa1, pb1, pc1)
        if (tid < 16) {
            float ta = gib[(size_t)128 * 4096 + tid];
            float tb = gib[(size_t)257 * 4096 + tid];
            float tc = gib[(size_t)386 * 4096 + tid];
            GATE(2048 + tid, ta, tb, tc)
        }
        __syncthreads();
    }

    for (int e = tid; e < 16 * 132; e += 1024) hstate[(size_t)b0 * 132 + e] = hs2[e];
    if (t0 + nt >= 60) {
        for (int e = tid; e < 2064; e += 1024) {
            int r = e & 15, j = e >> 4;
            float v = hs2[r * 132 + j];
            g_out[(size_t)(b0 + r) * 129 + j] = (v >= 0.f) ? v : 0.01f * v;
        }
        if (tid < 16) {
            float v = hs2[tid * 132 + 128];
            g_out[(size_t)(b0 + tid) * 129 + 128] = (v >= 0.f) ? v : 0.01f * v;
        }
    }
    #undef GATE
}

// ---------------------------------------------------------------------------
// Head: feat=[g,w] (258) -> mu, log_std -> sample, tanh, log_pi, normalize.
// ---------------------------------------------------------------------------
__global__ __launch_bounds__(256) void head_kernel(
    const float* __restrict__ gbuf, const float* __restrict__ wvec,
    const float* __restrict__ eps,
    const float* __restrict__ muwp, const float* __restrict__ lswp,
    const float* __restrict__ mub,  const float* __restrict__ lsb,
    float* __restrict__ out)
{
    __shared__ __attribute__((aligned(16))) float feat[16 * 260];
    __shared__ float PA[16 * 130];
    __shared__ float TERM[16 * 130];
    __shared__ float ROWSUM[16];
    __shared__ float ROWLOG[16];

    const int tid = threadIdx.x;
    const int b0  = blockIdx.x * 16;

    for (int i = tid; i < 16 * 260; i += 256) {
        int r = i / 260;
        int k = i - r * 260;
        float v = 0.f;
        if (k < 129)       v = gbuf[(size_t)(b0 + r) * 129 + k];
        else if (k < 258)  v = wvec[(size_t)(b0 + r) * 129 + (k - 129)];
        feat[i] = v;
    }
    __syncthreads();

    for (int idx = tid; idx < 16 * 129; idx += 256) {
        int r = idx & 15;
        int j = idx >> 4;
        const float4* fv = (const float4*)(feat + r * 260);
        const float4* mw = (const float4*)(muwp + (size_t)j * 260);
        const float4* lw = (const float4*)(lswp + (size_t)j * 260);
        float am = 0.f, al = 0.f;
        for (int k = 0; k < 65; ++k) {
            float4 f = fv[k];
            float4 m = mw[k];
            float4 l = lw[k];
            am += f.x * m.x + f.y * m.y + f.z * m.z + f.w * m.w;
            al += f.x * l.x + f.y * l.y + f.z * l.z + f.w * l.w;
        }
        float mu = am + mub[j];
        float ls = fminf(fmaxf(al + lsb[j], -20.f), 2.f);
        float sd = __expf(ls);
        float e  = eps[(size_t)(b0 + r) * 129 + j];
        float xv = mu + sd * e;
        float pa = fast_tanh(xv);
        float tt = (xv - mu) / sd;
        float term = -0.5f * tt * tt - ls - 0.91893853320467274f
                     - __logf(1.f - pa * pa + 1e-6f);
        PA[r * 130 + j]   = pa;
        TERM[r * 130 + j] = term;
    }
    __syncthreads();

    {
        int r = tid >> 4;
        int i = tid & 15;
        float sp = 0.f, st = 0.f;
        for (int j = i; j < 129; j += 16) {
            sp += PA[r * 130 + j];
            st += TERM[r * 130 + j];
        }
        for (int off = 8; off > 0; off >>= 1) {
            sp += __shfl_down(sp, off, 16);
            st += __shfl_down(st, off, 16);
        }
        if (i == 0) { ROWSUM[r] = sp + 129.f; ROWLOG[r] = st; }
    }
    __syncthreads();

    for (int idx = tid; idx < 16 * 129; idx += 256) {
        int r = idx & 15;
        int j = idx >> 4;
        out[(size_t)(b0 + r) * 129 + j] = (PA[r * 130 + j] + 1.f) / ROWSUM[r];
    }
    if (tid < 16)
        out[(size_t)4096 * 129 + b0 + tid] = ROWLOG[tid];
}

// ---------------------------------------------------------------------------
extern "C" void kernel_launch(void* const* d_in, const int* in_sizes, int n_in,
                              void* d_out, int out_size, void* d_ws, size_t ws_size,
                              hipStream_t stream)
{
    const float* x   = (const float*)d_in[0];
    const float* wv  = (const float*)d_in[1];
    const float* eps = (const float*)d_in[2];
    const float* c1w = (const float*)d_in[3];
    const float* c1b = (const float*)d_in[4];
    const float* c2w = (const float*)d_in[5];
    const float* c2b = (const float*)d_in[6];
    const float* Wih = (const float*)d_in[7];
    const float* Whh = (const float*)d_in[8];
    const float* bih = (const float*)d_in[9];
    const float* bhh = (const float*)d_in[10];
    const float* muw = (const float*)d_in[11];
    const float* mub = (const float*)d_in[12];
    const float* lsw = (const float*)d_in[13];
    const float* lsb = (const float*)d_in[14];

    float* ws     = (float*)d_ws;
    float* g      = ws + G_OFF;
    float* hstate = ws + HST_OFF;
    const short* awhh = (const short*)(ws + AWHH_OFF);
    const short* awih = (const short*)(ws + AWIH_OFF);
    float* muwp   = ws + MUWP_OFF;
    float* lswp   = ws + LSWP_OFF;
    short* sbf    = (short*)(ws + SBF_OFF);
    float* gic    = ws + GIC_OFF;
    float* outp   = (float*)d_out;

    // gic chunk size (deterministic given ws_size)
    long avail = (long)(ws_size / 4) - (long)GIC_OFF;
    int CT = 60;
    if (avail < 60L * PER_T_GIC) {
        CT = (int)(avail / PER_T_GIC);
        if (CT < 1) CT = 1;
        if (CT > 60) CT = 60;
    }

    const int prep_elems = 25 * 5 * 2 * 512 + 25 * 4 * 2 * 512 + 2 * (129 * 260);
    prep_pad<<<(prep_elems + 255) / 256, 256, 0, stream>>>(Whh, Wih, muw, lsw, ws);
    sbf_padzero<<<(60 * 32 * 128 * 2 + 255) / 256, 256, 0, stream>>>(sbf);
    conv_fused<<<dim3(6, BTOT), 256, 0, stream>>>(x, c1w, c1b, c2w, c2b, sbf);

    for (int t0 = 0; t0 < 60; t0 += CT) {
        int nt = 60 - t0; if (nt > CT) nt = CT;
        gi_mfma<<<dim3(32, 25), 512, 0, stream>>>(sbf, awih, gic, t0, nt);
        gru_mfma<<<256, 1024, 0, stream>>>(gic, awhh, bih, bhh, hstate, g, t0, nt);
    }
    head_kernel<<<BTOT / 16, 256, 0, stream>>>(g, wv, eps, muwp, lswp, mub, lsb, outp);
}

// Round 26
// 1318.516 us; speedup vs baseline: 1.1472x; 1.0015x over previous
//
#include <hip/hip_runtime.h>
#include <math.h>

// Problem constants
#define BTOT   4096
#define CIN    3
#define TIN    64
#define SIN    128

// ws layout (float offsets)  [R25: seq fp32 eliminated; sbf is full 60-t]
#define G_OFF      0                             // [4096][129]
#define HST_OFF    (G_OFF + 4096*129)            // [4096][132]
#define AWHH_OFF   (HST_OFF + 4096*132)          // [25][5][2][64][8] bf16 Whh frags
#define AWIH_OFF   (AWHH_OFF + 64000)            // [25][4][2][64][8] bf16 Wih frags
#define MUWP_OFF   (AWIH_OFF + 51200)            // [129][260]
#define LSWP_OFF   (MUWP_OFF + 129*260)          // [129][260]
#define SBF_OFF    (LSWP_OFF + 129*260)          // [60][32][10240 ull] = 60*655360 floats
#define GIC_OFF    (SBF_OFF + 60*655360)         // [CT][387][4096]

// per-t sizes
#define PER_T_GIC   (387 * 4096)
#define SBF_T_SH    1310720                      // shorts per t

typedef __attribute__((ext_vector_type(8))) short bf16x8;
typedef __attribute__((ext_vector_type(4))) float f32x4;

// Inline transcendentals (no libm calls in hot loops)
__device__ __forceinline__ float fast_tanh(float x) {
    float ax = fabsf(x);
    float t  = __expf(-2.f * ax);
    float r  = (1.f - t) / (1.f + t);
    return copysignf(r, x);
}
__device__ __forceinline__ float fast_sigmoid(float x) {
    return 1.f / (1.f + __expf(-x));
}
// bf16 round-to-nearest-even helpers (bit ops only)
__device__ __forceinline__ unsigned short f2bf(float x) {
    unsigned int u = __float_as_uint(x);
    unsigned int r = u + 0x7FFFu + ((u >> 16) & 1u);
    return (unsigned short)(r >> 16);
}
__device__ __forceinline__ float bf2f(unsigned short b) {
    return __uint_as_float(((unsigned int)b) << 16);
}

// ---------------------------------------------------------------------------
// Prep: bf16 hi/lo fragment tables for Whh (5 k-tiles) and Wih (4 k-tiles),
// plus fc weight padding. (Passing R18-R25.)
// ---------------------------------------------------------------------------
__global__ __launch_bounds__(256) void prep_pad(
    const float* __restrict__ Whh, const float* __restrict__ Wih,
    const float* __restrict__ muw, const float* __restrict__ lsw,
    float* __restrict__ ws)
{
    int idx = blockIdx.x * 256 + threadIdx.x;
    const int NHH = 25 * 5 * 2 * 512;   // 128000 shorts
    const int NIA = 25 * 4 * 2 * 512;   // 102400 shorts
    const int N2  = 129 * 260;
    if (idx < NHH) {
        int a      = idx;
        int frag   = a >> 9;
        int within = a & 511;
        int l      = within >> 3;
        int c      = within & 7;
        int half   = frag & 1;
        int q      = frag >> 1;
        int kt     = q % 5;
        int jt     = q / 5;
        int j      = jt * 16 + (l & 15);
        int k      = kt * 32 + (l >> 4) * 8 + c;
        float v    = (j < 387 && k < 129) ? Whh[(size_t)j * 129 + k] : 0.f;
        unsigned short hb = f2bf(v);
        ((short*)(ws + AWHH_OFF))[a] = (short)((half == 0) ? hb : f2bf(v - bf2f(hb)));
    } else if (idx < NHH + NIA) {
        int a      = idx - NHH;
        int frag   = a >> 9;
        int within = a & 511;
        int l      = within >> 3;
        int c      = within & 7;
        int half   = frag & 1;
        int q      = frag >> 1;
        int kt     = q & 3;
        int jt     = q >> 2;
        int j      = jt * 16 + (l & 15);
        int k      = kt * 32 + (l >> 4) * 8 + c;
        float v    = (j < 387 && k < 124) ? Wih[(size_t)j * 124 + k] : 0.f;
        unsigned short hb = f2bf(v);
        ((short*)(ws + AWIH_OFF))[a] = (short)((half == 0) ? hb : f2bf(v - bf2f(hb)));
    } else if (idx < NHH + NIA + N2) {
        int i = idx - NHH - NIA; int j = i / 260, k = i - j * 260;
        ws[MUWP_OFF + i] = (k < 258) ? muw[j * 258 + k] : 0.f;
    } else if (idx < NHH + NIA + 2 * N2) {
        int i = idx - NHH - NIA - N2; int j = i / 260, k = i - j * 260;
        ws[LSWP_OFF + i] = (k < 258) ? lsw[j * 258 + k] : 0.f;
    }
}

// ---------------------------------------------------------------------------
// sbf_padzero — passing R25 (unchanged).
// ---------------------------------------------------------------------------
__global__ __launch_bounds__(256) void sbf_padzero(short* __restrict__ sbf)
{
    int a = blockIdx.x * 256 + threadIdx.x;
    if (a >= 60 * 32 * 128 * 2) return;
    int half  = a & 1;
    int bi    = (a >> 1) & 127;
    int chunk = (a >> 8) & 31;
    int t     = a >> 13;
    size_t s = (size_t)t * SBF_T_SH + (size_t)chunk * 40960
             + (size_t)(6 + half) * 5120 + (size_t)bi * 40 + 3 * 8 + 4;
    *(unsigned long long*)(sbf + s) = 0ull;
}

// ---------------------------------------------------------------------------
// conv_fused v6 (R26): conv1 uses ROTATING ACCUMULATORS (X,Y,Z) + single-row
// double buffer. R25 diagnosis: 3-set window had prefetch distance 0 on the
// newest row (584us vs ~150us VALU floor). Now row r+1 loads while row r
// feeds 3 partial outputs (kt0->t=r, kt1->t=r-1, kt2->t=r-2); output r-2
// finalizes per step. Regs: 2 row bufs (36) + 3 accs (12) + 27 weights
// ~= 100 VGPR -- fits the 128 no-spill budget (R22: 4-set window at ~190
// spilled). conv2 writes seqbf directly (R25, unchanged).
// ---------------------------------------------------------------------------
#define RACC4(A0,A1,A2,A3, F4_, F2_, W0_, W1_, W2_) \
    A0 += (F4_).x*(W0_) + (F4_).y*(W1_) + (F4_).z*(W2_); \
    A1 += (F4_).y*(W0_) + (F4_).z*(W1_) + (F4_).w*(W2_); \
    A2 += (F4_).z*(W0_) + (F4_).w*(W1_) + (F2_).x*(W2_); \
    A3 += (F4_).w*(W0_) + (F2_).x*(W1_) + (F2_).y*(W2_);

#define LDSET(S, TR_) { \
    S##0_4 = *(const float4*)(xc0 + (TR_) * 128 + s0); \
    S##0_2 = *(const float2*)(xc0 + (TR_) * 128 + f2c); \
    S##1_4 = *(const float4*)(xc1 + (TR_) * 128 + s0); \
    S##1_2 = *(const float2*)(xc1 + (TR_) * 128 + f2c); \
    S##2_4 = *(const float4*)(xc2 + (TR_) * 128 + s0); \
    S##2_2 = *(const float2*)(xc2 + (TR_) * 128 + f2c); }

#define ACC_INIT(P) { P##0 = bo; P##1 = bo; P##2 = bo; P##3 = bo; }

// row-set S contributes its 3 channels with weight-row kt=K to acc set P
#define CONTRIB(S, P, K) \
    RACC4(P##0,P##1,P##2,P##3, S##0_4, S##0_2, w0##K##0, w0##K##1, w0##K##2) \
    RACC4(P##0,P##1,P##2,P##3, S##1_4, S##1_2, w1##K##0, w1##K##1, w1##K##2) \
    RACC4(P##0,P##1,P##2,P##3, S##2_4, S##2_2, w2##K##0, w2##K##1, w2##K##2)

#define FIN(P, TQ_) { \
    float4 r_; \
    r_.x = (P##0 >= 0.f) ? P##0 : 0.01f * P##0; \
    r_.y = (P##1 >= 0.f) ? P##1 : 0.01f * P##1; \
    r_.z = (P##2 >= 0.f) ? P##2 : 0.01f * P##2; \
    r_.w = (P##3 >= 0.f) ? P##3 : 0.01f * P##3; \
    *(float4*)(h1t + (o * 12 + (TQ_)) * 128 + s0) = r_; }

#define C2SEG(o_, kt_, W0_, W1_, W2_) { \
    const float* rp_ = h1t + ((o_) * 12 + tq + (kt_)) * 128 + s0; \
    float4 v4_ = *(const float4*)rp_; \
    float2 v2_ = *(const float2*)(rp_ + 4); \
    acc0 += v4_.x*(W0_) + v4_.y*(W1_) + v4_.z*(W2_); \
    acc1 += v4_.y*(W0_) + v4_.z*(W1_) + v4_.w*(W2_); \
    acc2 += v4_.z*(W0_) + v4_.w*(W1_) + v2_.x*(W2_); \
    acc3 += v4_.w*(W0_) + v2_.x*(W1_) + v2_.y*(W2_); }

__global__ __launch_bounds__(256) void conv_fused(
    const float* __restrict__ x,
    const float* __restrict__ w1, const float* __restrict__ b1,
    const float* __restrict__ w2, const float* __restrict__ b2,
    short* __restrict__ sbf)
{
    __shared__ __attribute__((aligned(16))) float h1t[6 * 12 * 128];
    __shared__ float w1s[162];
    __shared__ float w2s[54];
    __shared__ float b1s[6];
    __shared__ float b2s;

    const int tid  = threadIdx.x;
    const int tile = blockIdx.x;   // 0..5
    const int bb   = blockIdx.y;   // batch
    const int T0   = tile * 10;

    if (tid < 162)                  w1s[tid] = w1[tid];
    if (tid >= 192 && tid < 246)    w2s[tid - 192] = w2[tid - 192];
    if (tid >= 248 && tid < 254)    b1s[tid - 248] = b1[tid - 248];
    if (tid == 255)                 b2s = b2[0];
    __syncthreads();

    // ---- conv1 + leaky: rotating accumulators, prefetch distance 1 ----
    if (tid < 192) {
        const int o   = tid >> 5;
        const int s0  = (tid & 31) * 4;
        const int f2c = (s0 < 124) ? (s0 + 4) : 122;   // clamp: junk cols only
        const float* wb = w1s + o * 27;
        float w000 = wb[0],  w001 = wb[1],  w002 = wb[2];
        float w010 = wb[3],  w011 = wb[4],  w012 = wb[5];
        float w020 = wb[6],  w021 = wb[7],  w022 = wb[8];
        float w100 = wb[9],  w101 = wb[10], w102 = wb[11];
        float w110 = wb[12], w111 = wb[13], w112 = wb[14];
        float w120 = wb[15], w121 = wb[16], w122 = wb[17];
        float w200 = wb[18], w201 = wb[19], w202 = wb[20];
        float w210 = wb[21], w211 = wb[22], w212 = wb[23];
        float w220 = wb[24], w221 = wb[25], w222 = wb[26];
        float bo = b1s[o];

        const float* xc0 = x + (size_t)bb * (3 * 64 * 128) + (size_t)T0 * 128;
        const float* xc1 = xc0 + 64 * 128;
        const float* xc2 = xc0 + 2 * 64 * 128;

        float4 S00_4, S01_4, S02_4, S10_4, S11_4, S12_4;
        float2 S00_2, S01_2, S02_2, S10_2, S11_2, S12_2;
        float X0, X1, X2, X3, Y0, Y1, Y2, Y3, Z0, Z1, Z2, Z3;

        // row r lives in S[r&1]; step r loads row r+1, consumes row r.
        LDSET(S0, 0)
        LDSET(S1, 1)   ACC_INIT(X) CONTRIB(S0, X, 0)                                      // r=0
        LDSET(S0, 2)   ACC_INIT(Y) CONTRIB(S1, Y, 0) CONTRIB(S1, X, 1)                    // r=1
        LDSET(S1, 3)   ACC_INIT(Z) CONTRIB(S0, Z, 0) CONTRIB(S0, Y, 1) CONTRIB(S0, X, 2)
                       FIN(X, 0)  ACC_INIT(X)                                             // r=2
        LDSET(S0, 4)   CONTRIB(S1, X, 0) CONTRIB(S1, Z, 1) CONTRIB(S1, Y, 2)
                       FIN(Y, 1)  ACC_INIT(Y)                                             // r=3
        LDSET(S1, 5)   CONTRIB(S0, Y, 0) CONTRIB(S0, X, 1) CONTRIB(S0, Z, 2)
                       FIN(Z, 2)  ACC_INIT(Z)                                             // r=4
        LDSET(S0, 6)   CONTRIB(S1, Z, 0) CONTRIB(S1, Y, 1) CONTRIB(S1, X, 2)
                       FIN(X, 3)  ACC_INIT(X)                                             // r=5
        LDSET(S1, 7)   CONTRIB(S0, X, 0) CONTRIB(S0, Z, 1) CONTRIB(S0, Y, 2)
                       FIN(Y, 4)  ACC_INIT(Y)                                             // r=6
        LDSET(S0, 8)   CONTRIB(S1, Y, 0) CONTRIB(S1, X, 1) CONTRIB(S1, Z, 2)
                       FIN(Z, 5)  ACC_INIT(Z)                                             // r=7
        LDSET(S1, 9)   CONTRIB(S0, Z, 0) CONTRIB(S0, Y, 1) CONTRIB(S0, X, 2)
                       FIN(X, 6)  ACC_INIT(X)                                             // r=8
        LDSET(S0, 10)  CONTRIB(S1, X, 0) CONTRIB(S1, Z, 1) CONTRIB(S1, Y, 2)
                       FIN(Y, 7)  ACC_INIT(Y)                                             // r=9
        LDSET(S1, 11)  CONTRIB(S0, Y, 0) CONTRIB(S0, X, 1) CONTRIB(S0, Z, 2)
                       FIN(Z, 8)  ACC_INIT(Z)                                             // r=10
        LDSET(S0, 12)  CONTRIB(S1, Z, 0) CONTRIB(S1, Y, 1) CONTRIB(S1, X, 2)
                       FIN(X, 9)                                                          // r=11
        LDSET(S1, 13)  CONTRIB(S0, Z, 1) CONTRIB(S0, Y, 2)
                       FIN(Y, 10)                                                         // r=12
                       CONTRIB(S1, Z, 2)
                       FIN(Z, 11)                                                         // r=13
    }
    __syncthreads();

    // ---- conv2 + leaky -> seqbf (bf16 hi/lo frag layout, R25) ----
    {
        float u000 = w2s[0],  u001 = w2s[1],  u002 = w2s[2];
        float u010 = w2s[3],  u011 = w2s[4],  u012 = w2s[5];
        float u020 = w2s[6],  u021 = w2s[7],  u022 = w2s[8];
        float u100 = w2s[9],  u101 = w2s[10], u102 = w2s[11];
        float u110 = w2s[12], u111 = w2s[13], u112 = w2s[14];
        float u120 = w2s[15], u121 = w2s[16], u122 = w2s[17];
        float u200 = w2s[18], u201 = w2s[19], u202 = w2s[20];
        float u210 = w2s[21], u211 = w2s[22], u212 = w2s[23];
        float u220 = w2s[24], u221 = w2s[25], u222 = w2s[26];
        float u300 = w2s[27], u301 = w2s[28], u302 = w2s[29];
        float u310 = w2s[30], u311 = w2s[31], u312 = w2s[32];
        float u320 = w2s[33], u321 = w2s[34], u322 = w2s[35];
        float u400 = w2s[36], u401 = w2s[37], u402 = w2s[38];
        float u410 = w2s[39], u411 = w2s[40], u412 = w2s[41];
        float u420 = w2s[42], u421 = w2s[43], u422 = w2s[44];
        float u500 = w2s[45], u501 = w2s[46], u502 = w2s[47];
        float u510 = w2s[48], u511 = w2s[49], u512 = w2s[50];
        float u520 = w2s[51], u521 = w2s[52], u522 = w2s[53];
        float bo2 = b2s;
        const int chunk = bb >> 7;
        const int bi    = bb & 127;
        for (int idx = tid; idx < 310; idx += 256) {
            const int tq = idx / 31;
            const int s0 = (idx - tq * 31) * 4;
            float acc0 = bo2, acc1 = bo2, acc2 = bo2, acc3 = bo2;
            C2SEG(0, 0, u000, u001, u002)
            C2SEG(0, 1, u010, u011, u012)
            C2SEG(0, 2, u020, u021, u022)
            C2SEG(1, 0, u100, u101, u102)
            C2SEG(1, 1, u110, u111, u112)
            C2SEG(1, 2, u120, u121, u122)
            C2SEG(2, 0, u200, u201, u202)
            C2SEG(2, 1, u210, u211, u212)
            C2SEG(2, 2, u220, u221, u222)
            C2SEG(3, 0, u300, u301, u302)
            C2SEG(3, 1, u310, u311, u312)
            C2SEG(3, 2, u320, u321, u322)
            C2SEG(4, 0, u400, u401, u402)
            C2SEG(4, 1, u410, u411, u412)
            C2SEG(4, 2, u420, u421, u422)
            C2SEG(5, 0, u500, u501, u502)
            C2SEG(5, 1, u510, u511, u512)
            C2SEG(5, 2, u520, u521, u522)
            float r0 = (acc0 >= 0.f) ? acc0 : 0.01f * acc0;
            float r1 = (acc1 >= 0.f) ? acc1 : 0.01f * acc1;
            float r2 = (acc2 >= 0.f) ? acc2 : 0.01f * acc2;
            float r3 = (acc3 >= 0.f) ? acc3 : 0.01f * acc3;
            unsigned short H0 = f2bf(r0), H1 = f2bf(r1), H2 = f2bf(r2), H3 = f2bf(r3);
            unsigned short Q0 = f2bf(r0 - bf2f(H0));
            unsigned short Q1 = f2bf(r1 - bf2f(H1));
            unsigned short Q2 = f2bf(r2 - bf2f(H2));
            unsigned short Q3 = f2bf(r3 - bf2f(H3));
            unsigned long long hp = (unsigned long long)H0 | ((unsigned long long)H1 << 16)
                                  | ((unsigned long long)H2 << 32) | ((unsigned long long)H3 << 48);
            unsigned long long lp = (unsigned long long)Q0 | ((unsigned long long)Q1 << 16)
                                  | ((unsigned long long)Q2 << 32) | ((unsigned long long)Q3 << 48);
            const int kt   = s0 >> 5;
            const int ksub = (s0 >> 3) & 3;
            const int c0   = s0 & 7;
            size_t sb = (size_t)(T0 + tq) * SBF_T_SH + (size_t)chunk * 40960
                      + (size_t)(kt * 2) * 5120 + (size_t)bi * 40 + ksub * 8 + c0;
            *(unsigned long long*)(sbf + sb)        = hp;
            *(unsigned long long*)(sbf + sb + 5120) = lp;
        }
    }
}

// ---------------------------------------------------------------------------
// gi via MFMA v3 — passing R25 (unchanged).
// ---------------------------------------------------------------------------
__global__ __launch_bounds__(512) void gi_mfma(
    const short* __restrict__ sbf, const short* __restrict__ awih,
    float* __restrict__ gic, int t0, int nt)
{
    const int tid = threadIdx.x;
    const int l   = tid & 63;
    const int w   = tid >> 6;          // n-tile 0..7
    const int jt  = blockIdx.y;        // 0..24
    const int bx  = blockIdx.x;
    const int b0  = bx * 128;

    const bf16x8* at = (const bf16x8*)awih;
    const int abase = jt * 8 * 64 + l;
    bf16x8 Ah0 = at[abase + 0 * 128];
    bf16x8 Al0 = at[abase + 0 * 128 + 64];
    bf16x8 Ah1 = at[abase + 1 * 128];
    bf16x8 Al1 = at[abase + 1 * 128 + 64];
    bf16x8 Ah2 = at[abase + 2 * 128];
    bf16x8 Al2 = at[abase + 2 * 128 + 64];
    bf16x8 Ah3 = at[abase + 3 * 128];
    bf16x8 Al3 = at[abase + 3 * 128 + 64];

    const int bn   = w * 16 + (l & 15);
    const int ksub = l >> 4;
    const int off0 = bx * 40960 + (bn * 5 + ksub) * 8;
    const int row0 = ksub * 4;

    for (int tt = 0; tt < nt; ++tt) {
        const short* sb = sbf + (size_t)(t0 + tt) * SBF_T_SH + off0;
        f32x4 acc = {0.f, 0.f, 0.f, 0.f};
        #define GI_KT(KT, AH, AL) { \
            bf16x8 bh = *(const bf16x8*)(sb + ((KT) * 2 + 0) * 5120); \
            bf16x8 bl = *(const bf16x8*)(sb + ((KT) * 2 + 1) * 5120); \
            acc = __builtin_amdgcn_mfma_f32_16x16x32_bf16(AL, bh, acc, 0, 0, 0); \
            acc = __builtin_amdgcn_mfma_f32_16x16x32_bf16(AH, bl, acc, 0, 0, 0); \
            acc = __builtin_amdgcn_mfma_f32_16x16x32_bf16(AH, bh, acc, 0, 0, 0); }
        GI_KT(0, Ah0, Al0)
        GI_KT(1, Ah1, Al1)
        GI_KT(2, Ah2, Al2)
        GI_KT(3, Ah3, Al3)
        #undef GI_KT

        float* gt = gic + (size_t)tt * 387 * 4096;
        #pragma unroll
        for (int i = 0; i < 4; ++i) {
            int j = jt * 16 + row0 + i;
            if (j < 387)
                gt[(size_t)j * 4096 + b0 + bn] = acc[i];
        }
    }
}

// ---------------------------------------------------------------------------
// GRU recurrence via MFMA v2 — passing R24/R25 (unchanged).
// ---------------------------------------------------------------------------
__global__ __launch_bounds__(1024) void gru_mfma(
    const float* __restrict__ gic, const short* __restrict__ awhh,
    const float* __restrict__ bih, const float* __restrict__ bhh,
    float* __restrict__ hstate, float* __restrict__ g_out,
    int t0, int nt)
{
    __shared__ __attribute__((aligned(16))) short hbf[2 * 16 * 168];
    __shared__ float hs2[16 * 132];
    __shared__ float GHb[16 * 390];
    __shared__ float bihS[387];
    __shared__ float bhhS[387];

    const int tid  = threadIdx.x;
    const int l    = tid & 63;
    const int w    = tid >> 6;        // wave 0..15
    const int b0   = blockIdx.x * 16;
    const int bcol = l & 15;
    const int krow = l >> 4;
    const bool has1 = (w < 9);        // second tile jt = 16+w

    if (tid < 387) { bihS[tid] = bih[tid]; bhhS[tid] = bhh[tid]; }
    for (int e = tid; e < 2688; e += 1024) ((unsigned int*)hbf)[e] = 0u;
    if (t0 == 0) {
        for (int e = tid; e < 16 * 132; e += 1024) hs2[e] = 0.f;
        __syncthreads();
    } else {
        for (int e = tid; e < 16 * 132; e += 1024) hs2[e] = hstate[(size_t)b0 * 132 + e];
        __syncthreads();
        for (int e = tid; e < 2064; e += 1024) {
            int r = e & 15, j = e >> 4;
            float v = hs2[r * 132 + j];
            unsigned short hb = f2bf(v);
            hbf[r * 168 + j]        = (short)hb;
            hbf[2688 + r * 168 + j] = (short)f2bf(v - bf2f(hb));
        }
        __syncthreads();
    }

    const bf16x8* at = (const bf16x8*)awhh;

    #define GATE(E, PGA, PGB, PGC) { \
        int r_ = (E) & 15, j_ = (E) >> 4; \
        float pr_  = (PGA) + GHb[r_ * 390 + j_]       + bihS[j_]       + bhhS[j_]; \
        float pz_  = (PGB) + GHb[r_ * 390 + 129 + j_] + bihS[129 + j_] + bhhS[129 + j_]; \
        float gin_ = (PGC) + bihS[258 + j_]; \
        float ghn_ = GHb[r_ * 390 + 258 + j_] + bhhS[258 + j_]; \
        float rg_ = fast_sigmoid(pr_); \
        float zg_ = fast_sigmoid(pz_); \
        float nn_ = fast_tanh(gin_ + rg_ * ghn_); \
        float hn_ = (1.f - zg_) * nn_ + zg_ * hs2[r_ * 132 + j_]; \
        hs2[r_ * 132 + j_] = hn_; \
        unsigned short hb_ = f2bf(hn_); \
        hbf[r_ * 168 + j_]        = (short)hb_; \
        hbf[2688 + r_ * 168 + j_] = (short)f2bf(hn_ - bf2f(hb_)); }

    for (int tt = 0; tt < nt; ++tt) {
        const float* gib = gic + (size_t)tt * 387 * 4096 + b0;
        float pa0, pb0, pc0, pa1, pb1, pc1;
        {
            int r = tid & 15, j = tid >> 4;
            pa0 = gib[(size_t)j * 4096 + r];
            pb0 = gib[(size_t)(129 + j) * 4096 + r];
            pc0 = gib[(size_t)(258 + j) * 4096 + r];
            int e = tid + 1024; r = e & 15; j = e >> 4;   // e <= 2047 < 2064
            pa1 = gib[(size_t)j * 4096 + r];
            pb1 = gib[(size_t)(129 + j) * 4096 + r];
            pc1 = gib[(size_t)(258 + j) * 4096 + r];
        }

        f32x4 acc0 = {0.f,0.f,0.f,0.f}, acc1 = {0.f,0.f,0.f,0.f};
        #pragma unroll
        for (int kt = 0; kt < 5; ++kt) {
            bf16x8 bh = *(const bf16x8*)(hbf + bcol * 168 + kt * 32 + krow * 8);
            bf16x8 bl = *(const bf16x8*)(hbf + 2688 + bcol * 168 + kt * 32 + krow * 8);
            {
                int fb = ((w * 5 + kt) * 2) * 64 + l;
                bf16x8 Ah = at[fb], Al = at[fb + 64];
                acc0 = __builtin_amdgcn_mfma_f32_16x16x32_bf16(Al, bh, acc0, 0, 0, 0);
                acc0 = __builtin_amdgcn_mfma_f32_16x16x32_bf16(Ah, bl, acc0, 0, 0, 0);
                acc0 = __builtin_amdgcn_mfma_f32_16x16x32_bf16(Ah, bh, acc0, 0, 0, 0);
            }
            if (has1) {
                int fb = (((16 + w) * 5 + kt) * 2) * 64 + l;
                bf16x8 Ah = at[fb], Al = at[fb + 64];
                acc1 = __builtin_amdgcn_mfma_f32_16x16x32_bf16(Al, bh, acc1, 0, 0, 0);
                acc1 = __builtin_amdgcn_mfma_f32_16x16x32_bf16(Ah, bl, acc1, 0, 0, 0);
                acc1 = __builtin_amdgcn_mfma_f32_16x16x32_bf16(Ah, bh, acc1, 0, 0, 0);
            }
        }
        {
            int rb = bcol * 390;
            int j0 = w * 16 + krow * 4;          // jt = w: j <= 255, always valid
            GHb[rb + j0 + 0] = acc0[0];
            GHb[rb + j0 + 1] = acc0[1];
            GHb[rb + j0 + 2] = acc0[2];
            GHb[rb + j0 + 3] = acc0[3];
            if (has1) {
                if (w < 8) {                      // jt 16..23: j <= 383, valid
                    int j1 = (16 + w) * 16 + krow * 4;
                    GHb[rb + j1 + 0] = acc1[0];
                    GHb[rb + j1 + 1] = acc1[1];
                    GHb[rb + j1 + 2] = acc1[2];
                    GHb[rb + j1 + 3] = acc1[3];
                } else if (krow == 0) {           // jt 24: only j = 384..386
                    GHb[rb + 384] = acc1[0];
                    GHb[rb + 385] = acc1[1];
                    GHb[rb + 386] = acc1[2];
                }
            }
        }
        __syncthreads();

        GATE(tid,        pa0, pb0, pc0)
        GATE(tid + 1024, pa1, pb1, pc1)
        if (tid < 16) {
            float ta = gib[(size_t)128 * 4096 + tid];
            float tb = gib[(size_t)257 * 4096 + tid];
            float tc = gib[(size_t)386 * 4096 + tid];
            GATE(2048 + tid, ta, tb, tc)
        }
        __syncthreads();
    }

    for (int e = tid; e < 16 * 132; e += 1024) hstate[(size_t)b0 * 132 + e] = hs2[e];
    if (t0 + nt >= 60) {
        for (int e = tid; e < 2064; e += 1024) {
            int r = e & 15, j = e >> 4;
            float v = hs2[r * 132 + j];
            g_out[(size_t)(b0 + r) * 129 + j] = (v >= 0.f) ? v : 0.01f * v;
        }
        if (tid < 16) {
            float v = hs2[tid * 132 + 128];
            g_out[(size_t)(b0 + tid) * 129 + 128] = (v >= 0.f) ? v : 0.01f * v;
        }
    }
    #undef GATE
}

// ---------------------------------------------------------------------------
// Head: feat=[g,w] (258) -> mu, log_std -> sample, tanh, log_pi, normalize.
// ---------------------------------------------------------------------------
__global__ __launch_bounds__(256) void head_kernel(
    const float* __restrict__ gbuf, const float* __restrict__ wvec,
    const float* __restrict__ eps,
    const float* __restrict__ muwp, const float* __restrict__ lswp,
    const float* __restrict__ mub,  const float* __restrict__ lsb,
    float* __restrict__ out)
{
    __shared__ __attribute__((aligned(16))) float feat[16 * 260];
    __shared__ float PA[16 * 130];
    __shared__ float TERM[16 * 130];
    __shared__ float ROWSUM[16];
    __shared__ float ROWLOG[16];

    const int tid = threadIdx.x;
    const int b0  = blockIdx.x * 16;

    for (int i = tid; i < 16 * 260; i += 256) {
        int r = i / 260;
        int k = i - r * 260;
        float v = 0.f;
        if (k < 129)       v = gbuf[(size_t)(b0 + r) * 129 + k];
        else if (k < 258)  v = wvec[(size_t)(b0 + r) * 129 + (k - 129)];
        feat[i] = v;
    }
    __syncthreads();

    for (int idx = tid; idx < 16 * 129; idx += 256) {
        int r = idx & 15;
        int j = idx >> 4;
        const float4* fv = (const float4*)(feat + r * 260);
        const float4* mw = (const float4*)(muwp + (size_t)j * 260);
        const float4* lw = (const float4*)(lswp + (size_t)j * 260);
        float am = 0.f, al = 0.f;
        for (int k = 0; k < 65; ++k) {
            float4 f = fv[k];
            float4 m = mw[k];
            float4 l = lw[k];
            am += f.x * m.x + f.y * m.y + f.z * m.z + f.w * m.w;
            al += f.x * l.x + f.y * l.y + f.z * l.z + f.w * l.w;
        }
        float mu = am + mub[j];
        float ls = fminf(fmaxf(al + lsb[j], -20.f), 2.f);
        float sd = __expf(ls);
        float e  = eps[(size_t)(b0 + r) * 129 + j];
        float xv = mu + sd * e;
        float pa = fast_tanh(xv);
        float tt = (xv - mu) / sd;
        float term = -0.5f * tt * tt - ls - 0.91893853320467274f
                     - __logf(1.f - pa * pa + 1e-6f);
        PA[r * 130 + j]   = pa;
        TERM[r * 130 + j] = term;
    }
    __syncthreads();

    {
        int r = tid >> 4;
        int i = tid & 15;
        float sp = 0.f, st = 0.f;
        for (int j = i; j < 129; j += 16) {
            sp += PA[r * 130 + j];
            st += TERM[r * 130 + j];
        }
        for (int off = 8; off > 0; off >>= 1) {
            sp += __shfl_down(sp, off, 16);
            st += __shfl_down(st, off, 16);
        }
        if (i == 0) { ROWSUM[r] = sp + 129.f; ROWLOG[r] = st; }
    }
    __syncthreads();

    for (int idx = tid; idx < 16 * 129; idx += 256) {
        int r = idx & 15;
        int j = idx >> 4;
        out[(size_t)(b0 + r) * 129 + j] = (PA[r * 130 + j] + 1.f) / ROWSUM[r];
    }
    if (tid < 16)
        out[(size_t)4096 * 129 + b0 + tid] = ROWLOG[tid];
}

// ---------------------------------------------------------------------------
extern "C" void kernel_launch(void* const* d_in, const int* in_sizes, int n_in,
                              void* d_out, int out_size, void* d_ws, size_t ws_size,
                              hipStream_t stream)
{
    const float* x   = (const float*)d_in[0];
    const float* wv  = (const float*)d_in[1];
    const float* eps = (const float*)d_in[2];
    const float* c1w = (const float*)d_in[3];
    const float* c1b = (const float*)d_in[4];
    const float* c2w = (const float*)d_in[5];
    const float* c2b = (const float*)d_in[6];
    const float* Wih = (const float*)d_in[7];
    const float* Whh = (const float*)d_in[8];
    const float* bih = (const float*)d_in[9];
    const float* bhh = (const float*)d_in[10];
    const float* muw = (const float*)d_in[11];
    const float* mub = (const float*)d_in[12];
    const float* lsw = (const float*)d_in[13];
    const float* lsb = (const float*)d_in[14];

    float* ws     = (float*)d_ws;
    float* g      = ws + G_OFF;
    float* hstate = ws + HST_OFF;
    const short* awhh = (const short*)(ws + AWHH_OFF);
    const short* awih = (const short*)(ws + AWIH_OFF);
    float* muwp   = ws + MUWP_OFF;
    float* lswp   = ws + LSWP_OFF;
    short* sbf    = (short*)(ws + SBF_OFF);
    float* gic    = ws + GIC_OFF;
    float* outp   = (float*)d_out;

    // gic chunk size (deterministic given ws_size)
    long avail = (long)(ws_size / 4) - (long)GIC_OFF;
    int CT = 60;
    if (avail < 60L * PER_T_GIC) {
        CT = (int)(avail / PER_T_GIC);
        if (CT < 1) CT = 1;
        if (CT > 60) CT = 60;
    }

    const int prep_elems = 25 * 5 * 2 * 512 + 25 * 4 * 2 * 512 + 2 * (129 * 260);
    prep_pad<<<(prep_elems + 255) / 256, 256, 0, stream>>>(Whh, Wih, muw, lsw, ws);
    sbf_padzero<<<(60 * 32 * 128 * 2 + 255) / 256, 256, 0, stream>>>(sbf);
    conv_fused<<<dim3(6, BTOT), 256, 0, stream>>>(x, c1w, c1b, c2w, c2b, sbf);

    for (int t0 = 0; t0 < 60; t0 += CT) {
        int nt = 60 - t0; if (nt > CT) nt = CT;
        gi_mfma<<<dim3(32, 25), 512, 0, stream>>>(sbf, awih, gic, t0, nt);
        gru_mfma<<<256, 1024, 0, stream>>>(gic, awhh, bih, bhh, hstate, g, t0, nt);
    }
    head_kernel<<<BTOT / 16, 256, 0, stream>>>(g, wv, eps, muwp, lswp, mub, lsb, outp);
}